// Round 1
// baseline (1034.009 us; speedup 1.0000x reference)
//
#include <hip/hip_runtime.h>
#include <math.h>

#define NH 128          // hidden size
#define NI 6            // input size
#define SIGMA_REC 0.15f
#define WARM 384        // warmup steps (R16/R17: absmax at 384 == f16 floor)
#define NCHB 64         // R18: chunks per batch-group. MFMA scan: grid =
                        // (B/32) x NCHB = 256 blocks (1 wave/CU); critical
                        // path = WARM + ceil(2999/64) = 431 steps (was 759).

typedef __fp16 h2v __attribute__((ext_vector_type(2)));
typedef unsigned int vu4 __attribute__((ext_vector_type(4)));
typedef __fp16 f16x8 __attribute__((ext_vector_type(8)));
typedef float f32x16 __attribute__((ext_vector_type(16)));

__device__ __forceinline__ unsigned int pkh(float a, float b) {
    h2v h = __builtin_amdgcn_cvt_pkrtz(a, b);   // pack 2 f32 -> 2 f16 (RTZ)
    return __builtin_bit_cast(unsigned int, h);
}
#define H2(u) __builtin_bit_cast(h2v, (unsigned int)(u))

struct U6 { float2 a, b, c; };

// fallback-kernel helpers (R12-proven)
#define DOT_OCT(j, xv) \
    c00 = __builtin_amdgcn_fdot2(H2(a##j.x), H2((xv).x), c00, false); \
    c01 = __builtin_amdgcn_fdot2(H2(a##j.y), H2((xv).y), c01, false); \
    c02 = __builtin_amdgcn_fdot2(H2(a##j.z), H2((xv).z), c02, false); \
    c03 = __builtin_amdgcn_fdot2(H2(a##j.w), H2((xv).w), c03, false); \
    c10 = __builtin_amdgcn_fdot2(H2(b##j.x), H2((xv).x), c10, false); \
    c11 = __builtin_amdgcn_fdot2(H2(b##j.y), H2((xv).y), c11, false); \
    c12 = __builtin_amdgcn_fdot2(H2(b##j.z), H2((xv).z), c12, false); \
    c13 = __builtin_amdgcn_fdot2(H2(b##j.w), H2((xv).w), c13, false)

#define LDW(j) vu4 a##j, b##j; { \
    const float4* q0 = reinterpret_cast<const float4*>(wr0 + 8 * (j)); \
    const float4* q1 = reinterpret_cast<const float4*>(wr1 + 8 * (j)); \
    float4 f0 = q0[0], f1 = q0[1], g0 = q1[0], g1 = q1[1]; \
    a##j = (vu4){pkh(f0.x, f0.y), pkh(f0.z, f0.w), pkh(f1.x, f1.y), pkh(f1.z, f1.w)}; \
    b##j = (vu4){pkh(g0.x, g0.y), pkh(g0.z, g0.w), pkh(g1.x, g1.y), pkh(g1.z, g1.w)}; }

#define PIN_AB() \
    asm volatile("" : "+v"(a0), "+v"(a1), "+v"(a2),  "+v"(a3), \
                      "+v"(a4), "+v"(a5), "+v"(a6),  "+v"(a7), \
                      "+v"(a8), "+v"(a9), "+v"(a10), "+v"(a11), \
                      "+v"(a12), "+v"(a13), "+v"(a14), "+v"(a15)); \
    asm volatile("" : "+v"(b0), "+v"(b1), "+v"(b2),  "+v"(b3), \
                      "+v"(b4), "+v"(b5), "+v"(b6),  "+v"(b7), \
                      "+v"(b8), "+v"(b9), "+v"(b10), "+v"(b11), \
                      "+v"(b12), "+v"(b13), "+v"(b14), "+v"(b15))

// ---------------------------------------------------------------------------
// Kernel 0: precompute drive d[b,t,n] = u.W_in + scale*nz + p, packed f16.
// (UNCHANGED from R17 — layout dpre[b][t][dword i] = pkh(d(2i), d(2i+1)).)
// ---------------------------------------------------------------------------
__global__ __launch_bounds__(256) void drive_kernel(
    const float* __restrict__ u,      // [B,T,6]
    const float* __restrict__ p,      // [B,128]
    const float* __restrict__ alpha,  // [1]
    const float* __restrict__ noise,  // [B,T,128]
    const float* __restrict__ W_in,   // [128,6]
    unsigned int* __restrict__ dpre,  // [B*T*64]
    int B, int T)
{
    const float av    = alpha[0];
    const float scale = sqrtf(2.0f * av * SIGMA_REC * SIGMA_REC);
    const size_t total = (size_t)B * T * 64;
    for (size_t idx = (size_t)blockIdx.x * 256 + threadIdx.x; idx < total;
         idx += (size_t)gridDim.x * 256) {
        const int    l  = (int)(idx & 63);
        const size_t bt = idx >> 6;
        const int    b  = (int)(bt / (unsigned)T);
        const int    t  = (int)(bt - (size_t)b * T);

        float2 nz = *reinterpret_cast<const float2*>(
            noise + ((size_t)b * T + t) * NH + 2 * l);
        const float2* ur = reinterpret_cast<const float2*>(
            u + ((size_t)b * T + t) * NI);
        float2 ua = ur[0], ub = ur[1], uc = ur[2];
        const float4* wv = reinterpret_cast<const float4*>(W_in + 2 * l * NI);
        float4 w0 = wv[0], w1 = wv[1], w2 = wv[2];   // rows 2l, 2l+1 (12 floats)
        float2 pv = *reinterpret_cast<const float2*>(p + (size_t)b * NH + 2 * l);

        float dx = fmaf(ua.x, w0.x, fmaf(ua.y, w0.y, fmaf(ub.x, w0.z,
                   fmaf(ub.y, w0.w, fmaf(uc.x, w1.x, fmaf(uc.y, w1.y,
                   fmaf(scale, nz.x, pv.x)))))));
        float dy = fmaf(ua.x, w1.z, fmaf(ua.y, w1.w, fmaf(ub.x, w2.x,
                   fmaf(ub.y, w2.y, fmaf(uc.x, w2.z, fmaf(uc.y, w2.w,
                   fmaf(scale, nz.y, pv.y)))))));
        dpre[idx] = pkh(dx, dy);
    }
}

// ---------------------------------------------------------------------------
// R18: MFMA chunked speculative scan. One wave per (batch-group of 32, chunk).
// Per step: y[32n-tile x 32b] += W-tile * x  via v_mfma_f32_32x32x16_f16.
//   A = W tile  : lane holds W[32*mt + (l&31)][16*kk + 8*(l>>5) + 0..7]
//   B = x       : lane holds x[16*kk + 8*(l>>5) + 0..7][b = l&31]
//   C/D         : lane holds (n = 32*mt + (e&3)+8*(e>>2)+4*(l>>5), b = l&31)
// C is initialized from the f16 drive d (free d-add). Both D and B keep the
// batch column = l&31, so the step-to-step D->B transform is only a lane+-32
// exchange of 16 packed dwords (shfl_xor(32), proven in the R17 kernel).
// ---------------------------------------------------------------------------
__global__ __attribute__((amdgpu_flat_work_group_size(64, 64),
                          amdgpu_waves_per_eu(1, 1)))
void rnn_scan_mfma(
    const float* __restrict__ W_rec,        // [128,128]
    const unsigned int* __restrict__ dpre,  // [B*T*64]
    float* __restrict__ states,             // [B,T,128]
    const float* __restrict__ alpha,        // [1]
    int T)
{
    const int bg    = blockIdx.x;        // batch group (32 rows)
    const int chunk = blockIdx.y;
    const int lane  = threadIdx.x;
    const int col   = lane & 31;         // batch within group
    const int hi    = lane >> 5;
    const int b     = bg * 32 + col;

    const int NS   = T - 1;                     // 2999 steps
    const int S    = (NS + NCHB - 1) / NCHB;    // 47
    const int s0   = chunk * S;
    if (s0 >= NS) return;
    const int e0   = min(NS, s0 + S);
    const int ws   = max(0, s0 - WARM);
    const int NSm1 = NS - 1;

    // ---- W fragments: Wf[mt][kk] covers W[32mt + col][16kk + 8hi .. +7] ----
    f16x8 Wf[4][8];
#pragma unroll
    for (int mt = 0; mt < 4; ++mt) {
        const float* wrow = W_rec + (size_t)(32 * mt + col) * NH + 8 * hi;
#pragma unroll
        for (int kk = 0; kk < 8; ++kk) {
            const float4* q = reinterpret_cast<const float4*>(wrow + 16 * kk);
            float4 f0 = q[0], f1 = q[1];
            vu4 uw = {pkh(f0.x, f0.y), pkh(f0.z, f0.w),
                      pkh(f1.x, f1.y), pkh(f1.z, f1.w)};
            Wf[mt][kk] = __builtin_bit_cast(f16x8, uw);
        }
    }

    const float av  = alpha[0];
    const float oma = 1.0f - av;

    const unsigned int* dp_b = dpre + (size_t)b * T * 64;
    float* st_b = states + (size_t)b * T * NH;

    // state in f32, D-layout: xs[mt*16 + g*4 + r1*2 + delta],
    //   n = 32*mt + 8*g + 4*hi + 2*r1 + delta, batch = col
    float xs[64];
#pragma unroll
    for (int i = 0; i < 64; ++i) xs[i] = 0.f;
    // B fragments of x (f16 dwords); zero = initial state
    unsigned Bfd[8][4];
#pragma unroll
    for (int kk = 0; kk < 8; ++kk)
#pragma unroll
        for (int j = 0; j < 4; ++j) Bfd[kk][j] = 0u;

    if (chunk == 0) {   // true t=0 state is zero; store it
        float4 z4 = make_float4(0.f, 0.f, 0.f, 0.f);
#pragma unroll
        for (int mt = 0; mt < 4; ++mt)
#pragma unroll
            for (int g = 0; g < 4; ++g)
                *reinterpret_cast<float4*>(st_b + 32 * mt + 8 * g + 4 * hi) = z4;
    }

    // d double-buffer: 16 uint2 per step (lane's 32 dwords of the 64-dword row)
    uint2 dA[16], dB[16];
#define LDDM(BUF, tt) { \
    const unsigned int* rp_ = dp_b + (size_t)(tt) * 64 + 2 * hi; \
    _Pragma("unroll") \
    for (int mt_ = 0; mt_ < 4; ++mt_) { \
        _Pragma("unroll") \
        for (int g_ = 0; g_ < 4; ++g_) \
            BUF[mt_ * 4 + g_] = \
                *reinterpret_cast<const uint2*>(rp_ + mt_ * 16 + g_ * 4); \
    } }

    LDDM(dA, ws)
    LDDM(dB, min(ws + 1, NSm1))

#define STEPM(tt, BUF) { \
    /* C-init = drive d (f16 -> f32), then free the buffer + prefetch t+2 */ \
    f32x16 C[4]; \
    _Pragma("unroll") \
    for (int mt_ = 0; mt_ < 4; ++mt_) { \
        _Pragma("unroll") \
        for (int g_ = 0; g_ < 4; ++g_) { \
            uint2 dw_ = BUF[mt_ * 4 + g_]; \
            h2v dl_ = H2(dw_.x), dh_ = H2(dw_.y); \
            C[mt_][4 * g_ + 0] = (float)dl_.x; \
            C[mt_][4 * g_ + 1] = (float)dl_.y; \
            C[mt_][4 * g_ + 2] = (float)dh_.x; \
            C[mt_][4 * g_ + 3] = (float)dh_.y; \
        } \
    } \
    LDDM(BUF, min((tt) + 2, NSm1)) \
    /* y = W*x + d : 4 independent accumulation chains, kk-major interleave */ \
    _Pragma("unroll") \
    for (int kk_ = 0; kk_ < 8; ++kk_) { \
        vu4 bu_ = {Bfd[kk_][0], Bfd[kk_][1], Bfd[kk_][2], Bfd[kk_][3]}; \
        f16x8 bb_ = __builtin_bit_cast(f16x8, bu_); \
        _Pragma("unroll") \
        for (int mt_ = 0; mt_ < 4; ++mt_) \
            C[mt_] = __builtin_amdgcn_mfma_f32_32x32x16_f16( \
                Wf[mt_][kk_], bb_, C[mt_], 0, 0, 0); \
    } \
    /* blend: x = oma*x + av*relu(y) */ \
    _Pragma("unroll") \
    for (int mt_ = 0; mt_ < 4; ++mt_) { \
        _Pragma("unroll") \
        for (int e_ = 0; e_ < 16; ++e_) { \
            float v_ = fmaxf(C[mt_][e_], 0.f); \
            xs[mt_ * 16 + e_] = fmaf(oma, xs[mt_ * 16 + e_], av * v_); \
        } \
    } \
    if ((tt) >= s0) { \
        float* row_ = st_b + (size_t)((tt) + 1) * NH + 4 * hi; \
        _Pragma("unroll") \
        for (int mt_ = 0; mt_ < 4; ++mt_) { \
            _Pragma("unroll") \
            for (int g_ = 0; g_ < 4; ++g_) \
                *reinterpret_cast<float4*>(row_ + 32 * mt_ + 8 * g_) = \
                    make_float4(xs[mt_ * 16 + g_ * 4 + 0], \
                                xs[mt_ * 16 + g_ * 4 + 1], \
                                xs[mt_ * 16 + g_ * 4 + 2], \
                                xs[mt_ * 16 + g_ * 4 + 3]); \
        } \
    } \
    /* pack to f16 pairs (n even/odd), then cross-half exchange -> B frags.  */ \
    /* Owned: n[2] = hi; needed: k[3] = hi. For each (mt,gp,r1):             */ \
    /*   u = P[g=2gp], v = P[g=2gp+1];                                       */ \
    /*   Bfd[2mt+gp][r1]   = {lo: u, hi: v-from-lo}   (k[2]=0 dword)         */ \
    /*   Bfd[2mt+gp][2+r1] = {lo: u-from-hi, hi: v}   (k[2]=1 dword)         */ \
    unsigned P_[32]; \
    _Pragma("unroll") \
    for (int i_ = 0; i_ < 32; ++i_) P_[i_] = pkh(xs[2 * i_], xs[2 * i_ + 1]); \
    _Pragma("unroll") \
    for (int mt_ = 0; mt_ < 4; ++mt_) { \
        _Pragma("unroll") \
        for (int gp_ = 0; gp_ < 2; ++gp_) { \
            _Pragma("unroll") \
            for (int r_ = 0; r_ < 2; ++r_) { \
                unsigned u_ = P_[mt_ * 8 + 4 * gp_ + r_]; \
                unsigned v_ = P_[mt_ * 8 + 4 * gp_ + 2 + r_]; \
                unsigned su_ = (unsigned)__shfl_xor((int)u_, 32); \
                unsigned sv_ = (unsigned)__shfl_xor((int)v_, 32); \
                Bfd[2 * mt_ + gp_][r_]     = hi ? sv_ : u_; \
                Bfd[2 * mt_ + gp_][2 + r_] = hi ? v_  : su_; \
            } \
        } \
    } }

    for (int t = ws; t < e0; t += 2) {
        STEPM(t, dA)
        if (t + 1 < e0) { STEPM(t + 1, dB) }
    }
#undef STEPM
#undef LDDM
}

// ---------------------------------------------------------------------------
// Fallback scan (R12 verbatim, exact, non-chunked): if ws_size too small.
// ---------------------------------------------------------------------------
__global__ __attribute__((amdgpu_flat_work_group_size(64, 64),
                          amdgpu_waves_per_eu(1, 1)))
void rnn_scan_fb(
    const float* __restrict__ u, const float* __restrict__ p,
    const float* __restrict__ alpha, const float* __restrict__ noise,
    const float* __restrict__ W_rec, const float* __restrict__ W_in,
    float* __restrict__ states, int T)
{
    const int b    = blockIdx.x;
    const int lane = threadIdx.x;
    const int n0   = lane * 2;

    __shared__ unsigned int xsh[64];

    const float* wr0 = W_rec + (size_t)n0 * NH;
    const float* wr1 = wr0 + NH;
    LDW(0)  LDW(1)  LDW(2)  LDW(3)  LDW(4)  LDW(5)  LDW(6)  LDW(7)
    LDW(8)  LDW(9)  LDW(10) LDW(11) LDW(12) LDW(13) LDW(14) LDW(15)
    PIN_AB();

    const float wiA0 = W_in[n0 * NI + 0], wiA1 = W_in[n0 * NI + 1];
    const float wiA2 = W_in[n0 * NI + 2], wiA3 = W_in[n0 * NI + 3];
    const float wiA4 = W_in[n0 * NI + 4], wiA5 = W_in[n0 * NI + 5];
    const float wiB0 = W_in[(n0 + 1) * NI + 0], wiB1 = W_in[(n0 + 1) * NI + 1];
    const float wiB2 = W_in[(n0 + 1) * NI + 2], wiB3 = W_in[(n0 + 1) * NI + 3];
    const float wiB4 = W_in[(n0 + 1) * NI + 4], wiB5 = W_in[(n0 + 1) * NI + 5];

    const float2 pn   = *reinterpret_cast<const float2*>(p + (size_t)b * NH + n0);
    const float av    = alpha[0];
    const float oma   = 1.0f - av;
    const float scale = sqrtf(2.0f * av * SIGMA_REC * SIGMA_REC);

    const float* noise_b = noise + (size_t)b * T * NH + n0;
    unsigned int zv;
    asm volatile("v_mov_b32 %0, 0" : "=v"(zv));
    const float* u_b = u + (size_t)b * T * NI + zv;
    float* st_ptr = states + (size_t)b * T * NH + n0 + NH;

    xsh[lane] = 0u;
    *reinterpret_cast<float2*>(states + (size_t)b * T * NH + n0) = make_float2(0.f, 0.f);
    float xo0 = 0.0f, xo1 = 0.0f;

    auto LDnz = [&](int t) {
        return *reinterpret_cast<const float2*>(noise_b + (size_t)t * NH);
    };
    auto loadU = [&](int t) {
        const float2* up = reinterpret_cast<const float2*>(u_b + (size_t)t * NI);
        U6 r; r.a = up[0]; r.b = up[1]; r.c = up[2]; return r;
    };
    auto mkd = [&](float2 nz, const U6& uu) {
        float dx = fmaf(uu.a.x, wiA0, fmaf(uu.a.y, wiA1, fmaf(uu.b.x, wiA2,
                   fmaf(uu.b.y, wiA3, fmaf(uu.c.x, wiA4, fmaf(uu.c.y, wiA5,
                   fmaf(scale, nz.x, pn.x)))))));
        float dy = fmaf(uu.a.x, wiB0, fmaf(uu.a.y, wiB1, fmaf(uu.b.x, wiB2,
                   fmaf(uu.b.y, wiB3, fmaf(uu.c.x, wiB4, fmaf(uu.c.y, wiB5,
                   fmaf(scale, nz.y, pn.y)))))));
        return make_float2(dx, dy);
    };
    auto step = [&](float2 d) {
        const vu4* xr = reinterpret_cast<const vu4*>(xsh);
        float c00 = 0.f, c01 = 0.f, c02 = 0.f, c03 = 0.f;
        float c10 = 0.f, c11 = 0.f, c12 = 0.f, c13 = 0.f;
        vu4 xv0 = xr[0], xv1 = xr[1], xv2 = xr[2], xv3 = xr[3];
        vu4 xv4 = xr[4], xv5 = xr[5], xv6 = xr[6], xv7 = xr[7];
        DOT_OCT(0, xv0);  DOT_OCT(1, xv1);  DOT_OCT(2, xv2);  DOT_OCT(3, xv3);
        vu4 xv8 = xr[8], xv9 = xr[9], xv10 = xr[10], xv11 = xr[11];
        DOT_OCT(4, xv4);  DOT_OCT(5, xv5);  DOT_OCT(6, xv6);  DOT_OCT(7, xv7);
        vu4 xv12 = xr[12], xv13 = xr[13], xv14 = xr[14], xv15 = xr[15];
        DOT_OCT(8, xv8);  DOT_OCT(9, xv9);  DOT_OCT(10, xv10); DOT_OCT(11, xv11);
        DOT_OCT(12, xv12); DOT_OCT(13, xv13); DOT_OCT(14, xv14); DOT_OCT(15, xv15);
        float pre0 = ((c00 + c01) + (c02 + c03)) + d.x;
        float pre1 = ((c10 + c11) + (c12 + c13)) + d.y;
        float xn0 = fmaf(oma, xo0, av * fmaxf(pre0, 0.f));
        float xn1 = fmaf(oma, xo1, av * fmaxf(pre1, 0.f));
        xo0 = xn0; xo1 = xn1;
        *reinterpret_cast<float2*>(st_ptr) = make_float2(xn0, xn1);
        st_ptr += NH;
        xsh[lane] = pkh(xn0, xn1);
    };

    float2 nz0 = LDnz(0), nz1 = LDnz(1), nz2 = LDnz(2), nz3 = LDnz(3);
    U6 u0 = loadU(0), u1 = loadU(1), u2 = loadU(2), u3 = loadU(3);
    float2 nzA0 = LDnz(4), nzA1 = LDnz(5);   U6 uA0 = loadU(4), uA1 = loadU(5);
    float2 nzB0 = LDnz(6), nzB1 = LDnz(7);   U6 uB0 = loadU(6), uB1 = loadU(7);
    float2 d0 = mkd(nz0, u0), d1 = mkd(nz1, u1);
    float2 d2 = mkd(nz2, u2), d3 = mkd(nz3, u3);

    int t = 0;
    for (; t + 1 < T - 1; t += 2) {
        const int t8 = min(t + 8, T - 1), t9 = min(t + 9, T - 1);
        float2 nzC0 = LDnz(t8), nzC1 = LDnz(t9);
        U6 uC0 = loadU(t8), uC1 = loadU(t9);
        float2 dE = mkd(nzA0, uA0), dF = mkd(nzA1, uA1);
        step(d0);
        step(d1);
        d0 = d2; d1 = d3; d2 = dE; d3 = dF;
        nzA0 = nzB0; nzA1 = nzB1; uA0 = uB0; uA1 = uB1;
        nzB0 = nzC0; nzB1 = nzC1; uB0 = uC0; uB1 = uC1;
    }
    if (t < T - 1) step(d0);
}

// ---------------------------------------------------------------------------
// Projection: out[r,o] = sum_n relu(states[r,n]) * W_out[o,n]
// ---------------------------------------------------------------------------
__global__ __launch_bounds__(256) void out_proj_kernel(
    const float* __restrict__ states,  // [rows,128]
    const float* __restrict__ W_out,   // [2,128]
    float* __restrict__ out,           // [rows,2]
    int rows)
{
    const int wave = threadIdx.x >> 6;
    const int lane = threadIdx.x & 63;
    const int l    = lane & 31;
    const int row  = blockIdx.x * 8 + wave * 2 + (lane >> 5);
    if (row >= rows) return;

    float4 s = *reinterpret_cast<const float4*>(states + (size_t)row * NH + l * 4);
    s.x = fmaxf(s.x, 0.f); s.y = fmaxf(s.y, 0.f);
    s.z = fmaxf(s.z, 0.f); s.w = fmaxf(s.w, 0.f);
    float4 wa = reinterpret_cast<const float4*>(W_out)[l];
    float4 wb = reinterpret_cast<const float4*>(W_out + NH)[l];
    float c0 = s.x * wa.x + s.y * wa.y + s.z * wa.z + s.w * wa.w;
    float c1 = s.x * wb.x + s.y * wb.y + s.z * wb.z + s.w * wb.w;

#pragma unroll
    for (int off = 16; off >= 1; off >>= 1) {
        c0 += __shfl_xor(c0, off);
        c1 += __shfl_xor(c1, off);
    }
    if (l == 0) {
        *reinterpret_cast<float2*>(out + (size_t)row * 2) = make_float2(c0, c1);
    }
}

// ---------------------------------------------------------------------------
extern "C" void kernel_launch(void* const* d_in, const int* in_sizes, int n_in,
                              void* d_out, int out_size, void* d_ws, size_t ws_size,
                              hipStream_t stream) {
    const float* u     = (const float*)d_in[0];
    const float* p     = (const float*)d_in[1];
    const float* alpha = (const float*)d_in[2];
    const float* noise = (const float*)d_in[3];
    const float* W_rec = (const float*)d_in[4];
    const float* W_in  = (const float*)d_in[5];
    const float* W_out = (const float*)d_in[6];

    const int B = in_sizes[1] / NH;           // 128
    const int T = in_sizes[0] / (B * NI);     // 3000

    float* out    = (float*)d_out;                    // [B,T,2]
    float* states = out + (size_t)B * T * 2;          // [B,T,128]

    const size_t need = (size_t)B * T * 64 * sizeof(unsigned int);  // 98.3 MB
    if (d_ws != nullptr && ws_size >= need && (B % 32) == 0) {
        unsigned int* dpre = (unsigned int*)d_ws;
        drive_kernel<<<2048, 256, 0, stream>>>(u, p, alpha, noise, W_in,
                                               dpre, B, T);
        dim3 grid(B / 32, NCHB);
        rnn_scan_mfma<<<grid, 64, 0, stream>>>(W_rec, dpre, states, alpha, T);
    } else {
        rnn_scan_fb<<<B, 64, 0, stream>>>(u, p, alpha, noise, W_rec, W_in,
                                          states, T);
    }

    const int rows = B * T;
    out_proj_kernel<<<(rows + 7) / 8, 256, 0, stream>>>(states, W_out, out, rows);
}

// Round 2
// 1006.408 us; speedup vs baseline: 1.0274x; 1.0274x over previous
//
#include <hip/hip_runtime.h>
#include <math.h>

#define NH 128          // hidden size
#define NI 6            // input size
#define SIGMA_REC 0.15f
#define WARM 384        // warmup steps (R16/R17: absmax at 384 == f16 floor)
#define NCHB 64         // chunks per batch-group: grid = (B/32) x 64 = 256
                        // blocks (1 wave/CU); path = WARM + 47 = 431 steps.

typedef __fp16 h2v __attribute__((ext_vector_type(2)));
typedef unsigned int vu4 __attribute__((ext_vector_type(4)));
typedef __fp16 f16x8 __attribute__((ext_vector_type(8)));
typedef float f32x16 __attribute__((ext_vector_type(16)));

__device__ __forceinline__ unsigned int pkh(float a, float b) {
    h2v h = __builtin_amdgcn_cvt_pkrtz(a, b);   // pack 2 f32 -> 2 f16 (RTZ)
    return __builtin_bit_cast(unsigned int, h);
}
#define H2(u) __builtin_bit_cast(h2v, (unsigned int)(u))

struct U6 { float2 a, b, c; };

// fallback-kernel helpers (R12-proven)
#define DOT_OCT(j, xv) \
    c00 = __builtin_amdgcn_fdot2(H2(a##j.x), H2((xv).x), c00, false); \
    c01 = __builtin_amdgcn_fdot2(H2(a##j.y), H2((xv).y), c01, false); \
    c02 = __builtin_amdgcn_fdot2(H2(a##j.z), H2((xv).z), c02, false); \
    c03 = __builtin_amdgcn_fdot2(H2(a##j.w), H2((xv).w), c03, false); \
    c10 = __builtin_amdgcn_fdot2(H2(b##j.x), H2((xv).x), c10, false); \
    c11 = __builtin_amdgcn_fdot2(H2(b##j.y), H2((xv).y), c11, false); \
    c12 = __builtin_amdgcn_fdot2(H2(b##j.z), H2((xv).z), c12, false); \
    c13 = __builtin_amdgcn_fdot2(H2(b##j.w), H2((xv).w), c13, false)

#define LDW(j) vu4 a##j, b##j; { \
    const float4* q0 = reinterpret_cast<const float4*>(wr0 + 8 * (j)); \
    const float4* q1 = reinterpret_cast<const float4*>(wr1 + 8 * (j)); \
    float4 f0 = q0[0], f1 = q0[1], g0 = q1[0], g1 = q1[1]; \
    a##j = (vu4){pkh(f0.x, f0.y), pkh(f0.z, f0.w), pkh(f1.x, f1.y), pkh(f1.z, f1.w)}; \
    b##j = (vu4){pkh(g0.x, g0.y), pkh(g0.z, g0.w), pkh(g1.x, g1.y), pkh(g1.z, g1.w)}; }

#define PIN_AB() \
    asm volatile("" : "+v"(a0), "+v"(a1), "+v"(a2),  "+v"(a3), \
                      "+v"(a4), "+v"(a5), "+v"(a6),  "+v"(a7), \
                      "+v"(a8), "+v"(a9), "+v"(a10), "+v"(a11), \
                      "+v"(a12), "+v"(a13), "+v"(a14), "+v"(a15)); \
    asm volatile("" : "+v"(b0), "+v"(b1), "+v"(b2),  "+v"(b3), \
                      "+v"(b4), "+v"(b5), "+v"(b6),  "+v"(b7), \
                      "+v"(b8), "+v"(b9), "+v"(b10), "+v"(b11), \
                      "+v"(b12), "+v"(b13), "+v"(b14), "+v"(b15))

// ---------------------------------------------------------------------------
// Kernel 0: precompute drive d[b,t,n] = u.W_in + scale*nz + p, packed f16.
// (UNCHANGED — layout dpre[b][t][dword i] = pkh(d(2i), d(2i+1)).)
// ---------------------------------------------------------------------------
__global__ __launch_bounds__(256) void drive_kernel(
    const float* __restrict__ u,      // [B,T,6]
    const float* __restrict__ p,      // [B,128]
    const float* __restrict__ alpha,  // [1]
    const float* __restrict__ noise,  // [B,T,128]
    const float* __restrict__ W_in,   // [128,6]
    unsigned int* __restrict__ dpre,  // [B*T*64]
    int B, int T)
{
    const float av    = alpha[0];
    const float scale = sqrtf(2.0f * av * SIGMA_REC * SIGMA_REC);
    const size_t total = (size_t)B * T * 64;
    for (size_t idx = (size_t)blockIdx.x * 256 + threadIdx.x; idx < total;
         idx += (size_t)gridDim.x * 256) {
        const int    l  = (int)(idx & 63);
        const size_t bt = idx >> 6;
        const int    b  = (int)(bt / (unsigned)T);
        const int    t  = (int)(bt - (size_t)b * T);

        float2 nz = *reinterpret_cast<const float2*>(
            noise + ((size_t)b * T + t) * NH + 2 * l);
        const float2* ur = reinterpret_cast<const float2*>(
            u + ((size_t)b * T + t) * NI);
        float2 ua = ur[0], ub = ur[1], uc = ur[2];
        const float4* wv = reinterpret_cast<const float4*>(W_in + 2 * l * NI);
        float4 w0 = wv[0], w1 = wv[1], w2 = wv[2];   // rows 2l, 2l+1 (12 floats)
        float2 pv = *reinterpret_cast<const float2*>(p + (size_t)b * NH + 2 * l);

        float dx = fmaf(ua.x, w0.x, fmaf(ua.y, w0.y, fmaf(ub.x, w0.z,
                   fmaf(ub.y, w0.w, fmaf(uc.x, w1.x, fmaf(uc.y, w1.y,
                   fmaf(scale, nz.x, pv.x)))))));
        float dy = fmaf(ua.x, w1.z, fmaf(ua.y, w1.w, fmaf(ub.x, w2.x,
                   fmaf(ub.y, w2.y, fmaf(uc.x, w2.z, fmaf(uc.y, w2.w,
                   fmaf(scale, nz.y, pv.y)))))));
        dpre[idx] = pkh(dx, dy);
    }
}

// ---------------------------------------------------------------------------
// R19: MFMA chunked speculative scan, Wf PINNED IN AGPRs.
// R18 post-mortem: without a pin the compiler rematerialized the 128-dword W
// fragment set inside the step loop (re-load + re-pack every step, ~3K cyc).
// "+a" pins force AGPR residence (gfx950 MFMA reads A directly from AGPR);
// arch-VGPR demand drops to ~220 -> no spill, no remat.
//   A = W tile  : lane holds W[32*mt + (l&31)][16*kk + 8*(l>>5) + 0..7]
//   B = x       : lane holds x[16*kk + 8*(l>>5) + 0..7][b = l&31]
//   C/D         : lane holds (n = 32*mt + (e&3)+8*(e>>2)+4*(l>>5), b = l&31)
// C initialized from f16 drive d (free d-add). D->B is a lane+-32 exchange.
// ---------------------------------------------------------------------------
__global__ __attribute__((amdgpu_flat_work_group_size(64, 64),
                          amdgpu_waves_per_eu(1, 1)))
void rnn_scan_mfma(
    const float* __restrict__ W_rec,        // [128,128]
    const unsigned int* __restrict__ dpre,  // [B*T*64]
    float* __restrict__ states,             // [B,T,128]
    const float* __restrict__ alpha,        // [1]
    int T)
{
    const int bg    = blockIdx.x;        // batch group (32 rows)
    const int chunk = blockIdx.y;
    const int lane  = threadIdx.x;
    const int col   = lane & 31;         // batch within group
    const int hi    = lane >> 5;
    const int b     = bg * 32 + col;

    const int NS   = T - 1;                     // 2999 steps
    const int S    = (NS + NCHB - 1) / NCHB;    // 47
    const int s0   = chunk * S;
    if (s0 >= NS) return;
    const int e0   = min(NS, s0 + S);
    const int ws   = max(0, s0 - WARM);
    const int NSm1 = NS - 1;

    // ---- W fragments: Wf[mt][kk] covers W[32mt + col][16kk + 8hi .. +7] ----
    f16x8 Wf[4][8];
#pragma unroll
    for (int mt = 0; mt < 4; ++mt) {
        const float* wrow = W_rec + (size_t)(32 * mt + col) * NH + 8 * hi;
#pragma unroll
        for (int kk = 0; kk < 8; ++kk) {
            const float4* q = reinterpret_cast<const float4*>(wrow + 16 * kk);
            float4 f0 = q[0], f1 = q[1];
            vu4 uw = {pkh(f0.x, f0.y), pkh(f0.z, f0.w),
                      pkh(f1.x, f1.y), pkh(f1.z, f1.w)};
            Wf[mt][kk] = __builtin_bit_cast(f16x8, uw);
        }
    }
    // Pin to AGPRs: blocks rematerialization (asm output is opaque) and moves
    // 128 dwords off the arch-VGPR budget. Split: <=16 operands per asm.
    asm volatile("" : "+a"(Wf[0][0]), "+a"(Wf[0][1]), "+a"(Wf[0][2]), "+a"(Wf[0][3]),
                      "+a"(Wf[0][4]), "+a"(Wf[0][5]), "+a"(Wf[0][6]), "+a"(Wf[0][7]),
                      "+a"(Wf[1][0]), "+a"(Wf[1][1]), "+a"(Wf[1][2]), "+a"(Wf[1][3]),
                      "+a"(Wf[1][4]), "+a"(Wf[1][5]), "+a"(Wf[1][6]), "+a"(Wf[1][7]));
    asm volatile("" : "+a"(Wf[2][0]), "+a"(Wf[2][1]), "+a"(Wf[2][2]), "+a"(Wf[2][3]),
                      "+a"(Wf[2][4]), "+a"(Wf[2][5]), "+a"(Wf[2][6]), "+a"(Wf[2][7]),
                      "+a"(Wf[3][0]), "+a"(Wf[3][1]), "+a"(Wf[3][2]), "+a"(Wf[3][3]),
                      "+a"(Wf[3][4]), "+a"(Wf[3][5]), "+a"(Wf[3][6]), "+a"(Wf[3][7]));

    const float av  = alpha[0];
    const float oma = 1.0f - av;
    f32x16 omv, avv, z16;
#pragma unroll
    for (int i = 0; i < 16; ++i) { omv[i] = oma; avv[i] = av; z16[i] = 0.f; }

    const unsigned int* dp_b = dpre + (size_t)b * T * 64;
    float* st_b = states + (size_t)b * T * NH;

    // state in f32, D-layout: xsv[mt][g*4 + r1*2 + delta],
    //   n = 32*mt + 8*g + 4*hi + 2*r1 + delta, batch = col
    f32x16 xsv[4];
#pragma unroll
    for (int mt = 0; mt < 4; ++mt) xsv[mt] = z16;
    // B fragments of x (f16 dwords); zero = initial state
    unsigned Bfd[8][4];
#pragma unroll
    for (int kk = 0; kk < 8; ++kk)
#pragma unroll
        for (int j = 0; j < 4; ++j) Bfd[kk][j] = 0u;

    if (chunk == 0) {   // true t=0 state is zero; store it
        float4 z4 = make_float4(0.f, 0.f, 0.f, 0.f);
#pragma unroll
        for (int mt = 0; mt < 4; ++mt)
#pragma unroll
            for (int g = 0; g < 4; ++g)
                *reinterpret_cast<float4*>(st_b + 32 * mt + 8 * g + 4 * hi) = z4;
    }

    // single d buffer (depth-1 prefetch; refilled right after C-init so the
    // full step body hides the load latency). 16 uint2 = lane's 32 dwords.
    uint2 dA[16];
#define LDDM(BUF, tt) { \
    const unsigned int* rp_ = dp_b + (size_t)(tt) * 64 + 2 * hi; \
    _Pragma("unroll") \
    for (int mt_ = 0; mt_ < 4; ++mt_) { \
        _Pragma("unroll") \
        for (int g_ = 0; g_ < 4; ++g_) \
            BUF[mt_ * 4 + g_] = \
                *reinterpret_cast<const uint2*>(rp_ + mt_ * 16 + g_ * 4); \
    } }

    LDDM(dA, ws)

#define STEPM(tt) { \
    /* C-init = drive d (f16 -> f32); then refill dA for t+1 */ \
    f32x16 C[4]; \
    _Pragma("unroll") \
    for (int mt_ = 0; mt_ < 4; ++mt_) { \
        _Pragma("unroll") \
        for (int g_ = 0; g_ < 4; ++g_) { \
            uint2 dw_ = dA[mt_ * 4 + g_]; \
            h2v dl_ = H2(dw_.x), dh_ = H2(dw_.y); \
            C[mt_][4 * g_ + 0] = (float)dl_.x; \
            C[mt_][4 * g_ + 1] = (float)dl_.y; \
            C[mt_][4 * g_ + 2] = (float)dh_.x; \
            C[mt_][4 * g_ + 3] = (float)dh_.y; \
        } \
    } \
    LDDM(dA, min((tt) + 1, NSm1)) \
    /* y = W*x + d : 4 independent accumulation chains, kk-major interleave */ \
    _Pragma("unroll") \
    for (int kk_ = 0; kk_ < 8; ++kk_) { \
        vu4 bu_ = {Bfd[kk_][0], Bfd[kk_][1], Bfd[kk_][2], Bfd[kk_][3]}; \
        f16x8 bb_ = __builtin_bit_cast(f16x8, bu_); \
        _Pragma("unroll") \
        for (int mt_ = 0; mt_ < 4; ++mt_) \
            C[mt_] = __builtin_amdgcn_mfma_f32_32x32x16_f16( \
                Wf[mt_][kk_], bb_, C[mt_], 0, 0, 0); \
    } \
    /* blend: x = oma*x + av*relu(y)  (vector form -> v_pk_*_f32 capable) */ \
    _Pragma("unroll") \
    for (int mt_ = 0; mt_ < 4; ++mt_) { \
        f32x16 r_ = __builtin_elementwise_max(C[mt_], z16); \
        xsv[mt_] = __builtin_elementwise_fma(omv, xsv[mt_], avv * r_); \
    } \
    if ((tt) >= s0) { \
        float* row_ = st_b + (size_t)((tt) + 1) * NH + 4 * hi; \
        _Pragma("unroll") \
        for (int mt_ = 0; mt_ < 4; ++mt_) { \
            _Pragma("unroll") \
            for (int g_ = 0; g_ < 4; ++g_) \
                *reinterpret_cast<float4*>(row_ + 32 * mt_ + 8 * g_) = \
                    make_float4(xsv[mt_][g_ * 4 + 0], \
                                xsv[mt_][g_ * 4 + 1], \
                                xsv[mt_][g_ * 4 + 2], \
                                xsv[mt_][g_ * 4 + 3]); \
        } \
    } \
    /* pack to f16 pairs (n even/odd), then cross-half exchange -> B frags.  */ \
    /* Owned: n[2] = hi; needed: k[3] = hi. For each (mt,gp,r1):             */ \
    /*   u = P[g=2gp], v = P[g=2gp+1];                                       */ \
    /*   Bfd[2mt+gp][r1]   = {lo: u, hi: v-from-lo}   (k[2]=0 dword)         */ \
    /*   Bfd[2mt+gp][2+r1] = {lo: u-from-hi, hi: v}   (k[2]=1 dword)         */ \
    unsigned P_[32]; \
    _Pragma("unroll") \
    for (int i_ = 0; i_ < 32; ++i_) \
        P_[i_] = pkh(xsv[i_ >> 3][(2 * i_) & 15], xsv[i_ >> 3][(2 * i_ + 1) & 15]); \
    _Pragma("unroll") \
    for (int mt_ = 0; mt_ < 4; ++mt_) { \
        _Pragma("unroll") \
        for (int gp_ = 0; gp_ < 2; ++gp_) { \
            _Pragma("unroll") \
            for (int r_ = 0; r_ < 2; ++r_) { \
                unsigned u_ = P_[mt_ * 8 + 4 * gp_ + r_]; \
                unsigned v_ = P_[mt_ * 8 + 4 * gp_ + 2 + r_]; \
                unsigned su_ = (unsigned)__shfl_xor((int)u_, 32); \
                unsigned sv_ = (unsigned)__shfl_xor((int)v_, 32); \
                Bfd[2 * mt_ + gp_][r_]     = hi ? sv_ : u_; \
                Bfd[2 * mt_ + gp_][2 + r_] = hi ? v_  : su_; \
            } \
        } \
    } }

#pragma unroll 1
    for (int t = ws; t < e0; ++t) {
        STEPM(t)
    }
#undef STEPM
#undef LDDM
}

// ---------------------------------------------------------------------------
// Fallback scan (R12 verbatim, exact, non-chunked): if ws_size too small.
// ---------------------------------------------------------------------------
__global__ __attribute__((amdgpu_flat_work_group_size(64, 64),
                          amdgpu_waves_per_eu(1, 1)))
void rnn_scan_fb(
    const float* __restrict__ u, const float* __restrict__ p,
    const float* __restrict__ alpha, const float* __restrict__ noise,
    const float* __restrict__ W_rec, const float* __restrict__ W_in,
    float* __restrict__ states, int T)
{
    const int b    = blockIdx.x;
    const int lane = threadIdx.x;
    const int n0   = lane * 2;

    __shared__ unsigned int xsh[64];

    const float* wr0 = W_rec + (size_t)n0 * NH;
    const float* wr1 = wr0 + NH;
    LDW(0)  LDW(1)  LDW(2)  LDW(3)  LDW(4)  LDW(5)  LDW(6)  LDW(7)
    LDW(8)  LDW(9)  LDW(10) LDW(11) LDW(12) LDW(13) LDW(14) LDW(15)
    PIN_AB();

    const float wiA0 = W_in[n0 * NI + 0], wiA1 = W_in[n0 * NI + 1];
    const float wiA2 = W_in[n0 * NI + 2], wiA3 = W_in[n0 * NI + 3];
    const float wiA4 = W_in[n0 * NI + 4], wiA5 = W_in[n0 * NI + 5];
    const float wiB0 = W_in[(n0 + 1) * NI + 0], wiB1 = W_in[(n0 + 1) * NI + 1];
    const float wiB2 = W_in[(n0 + 1) * NI + 2], wiB3 = W_in[(n0 + 1) * NI + 3];
    const float wiB4 = W_in[(n0 + 1) * NI + 4], wiB5 = W_in[(n0 + 1) * NI + 5];

    const float2 pn   = *reinterpret_cast<const float2*>(p + (size_t)b * NH + n0);
    const float av    = alpha[0];
    const float oma   = 1.0f - av;
    const float scale = sqrtf(2.0f * av * SIGMA_REC * SIGMA_REC);

    const float* noise_b = noise + (size_t)b * T * NH + n0;
    unsigned int zv;
    asm volatile("v_mov_b32 %0, 0" : "=v"(zv));
    const float* u_b = u + (size_t)b * T * NI + zv;
    float* st_ptr = states + (size_t)b * T * NH + n0 + NH;

    xsh[lane] = 0u;
    *reinterpret_cast<float2*>(states + (size_t)b * T * NH + n0) = make_float2(0.f, 0.f);
    float xo0 = 0.0f, xo1 = 0.0f;

    auto LDnz = [&](int t) {
        return *reinterpret_cast<const float2*>(noise_b + (size_t)t * NH);
    };
    auto loadU = [&](int t) {
        const float2* up = reinterpret_cast<const float2*>(u_b + (size_t)t * NI);
        U6 r; r.a = up[0]; r.b = up[1]; r.c = up[2]; return r;
    };
    auto mkd = [&](float2 nz, const U6& uu) {
        float dx = fmaf(uu.a.x, wiA0, fmaf(uu.a.y, wiA1, fmaf(uu.b.x, wiA2,
                   fmaf(uu.b.y, wiA3, fmaf(uu.c.x, wiA4, fmaf(uu.c.y, wiA5,
                   fmaf(scale, nz.x, pn.x)))))));
        float dy = fmaf(uu.a.x, wiB0, fmaf(uu.a.y, wiB1, fmaf(uu.b.x, wiB2,
                   fmaf(uu.b.y, wiB3, fmaf(uu.c.x, wiB4, fmaf(uu.c.y, wiB5,
                   fmaf(scale, nz.y, pn.y)))))));
        return make_float2(dx, dy);
    };
    auto step = [&](float2 d) {
        const vu4* xr = reinterpret_cast<const vu4*>(xsh);
        float c00 = 0.f, c01 = 0.f, c02 = 0.f, c03 = 0.f;
        float c10 = 0.f, c11 = 0.f, c12 = 0.f, c13 = 0.f;
        vu4 xv0 = xr[0], xv1 = xr[1], xv2 = xr[2], xv3 = xr[3];
        vu4 xv4 = xr[4], xv5 = xr[5], xv6 = xr[6], xv7 = xr[7];
        DOT_OCT(0, xv0);  DOT_OCT(1, xv1);  DOT_OCT(2, xv2);  DOT_OCT(3, xv3);
        vu4 xv8 = xr[8], xv9 = xr[9], xv10 = xr[10], xv11 = xr[11];
        DOT_OCT(4, xv4);  DOT_OCT(5, xv5);  DOT_OCT(6, xv6);  DOT_OCT(7, xv7);
        vu4 xv12 = xr[12], xv13 = xr[13], xv14 = xr[14], xv15 = xr[15];
        DOT_OCT(8, xv8);  DOT_OCT(9, xv9);  DOT_OCT(10, xv10); DOT_OCT(11, xv11);
        DOT_OCT(12, xv12); DOT_OCT(13, xv13); DOT_OCT(14, xv14); DOT_OCT(15, xv15);
        float pre0 = ((c00 + c01) + (c02 + c03)) + d.x;
        float pre1 = ((c10 + c11) + (c12 + c13)) + d.y;
        float xn0 = fmaf(oma, xo0, av * fmaxf(pre0, 0.f));
        float xn1 = fmaf(oma, xo1, av * fmaxf(pre1, 0.f));
        xo0 = xn0; xo1 = xn1;
        *reinterpret_cast<float2*>(st_ptr) = make_float2(xn0, xn1);
        st_ptr += NH;
        xsh[lane] = pkh(xn0, xn1);
    };

    float2 nz0 = LDnz(0), nz1 = LDnz(1), nz2 = LDnz(2), nz3 = LDnz(3);
    U6 u0 = loadU(0), u1 = loadU(1), u2 = loadU(2), u3 = loadU(3);
    float2 nzA0 = LDnz(4), nzA1 = LDnz(5);   U6 uA0 = loadU(4), uA1 = loadU(5);
    float2 nzB0 = LDnz(6), nzB1 = LDnz(7);   U6 uB0 = loadU(6), uB1 = loadU(7);
    float2 d0 = mkd(nz0, u0), d1 = mkd(nz1, u1);
    float2 d2 = mkd(nz2, u2), d3 = mkd(nz3, u3);

    int t = 0;
    for (; t + 1 < T - 1; t += 2) {
        const int t8 = min(t + 8, T - 1), t9 = min(t + 9, T - 1);
        float2 nzC0 = LDnz(t8), nzC1 = LDnz(t9);
        U6 uC0 = loadU(t8), uC1 = loadU(t9);
        float2 dE = mkd(nzA0, uA0), dF = mkd(nzA1, uA1);
        step(d0);
        step(d1);
        d0 = d2; d1 = d3; d2 = dE; d3 = dF;
        nzA0 = nzB0; nzA1 = nzB1; uA0 = uB0; uA1 = uB1;
        nzB0 = nzC0; nzB1 = nzC1; uB0 = uC0; uB1 = uC1;
    }
    if (t < T - 1) step(d0);
}

// ---------------------------------------------------------------------------
// Projection: out[r,o] = sum_n relu(states[r,n]) * W_out[o,n]
// ---------------------------------------------------------------------------
__global__ __launch_bounds__(256) void out_proj_kernel(
    const float* __restrict__ states,  // [rows,128]
    const float* __restrict__ W_out,   // [2,128]
    float* __restrict__ out,           // [rows,2]
    int rows)
{
    const int wave = threadIdx.x >> 6;
    const int lane = threadIdx.x & 63;
    const int l    = lane & 31;
    const int row  = blockIdx.x * 8 + wave * 2 + (lane >> 5);
    if (row >= rows) return;

    float4 s = *reinterpret_cast<const float4*>(states + (size_t)row * NH + l * 4);
    s.x = fmaxf(s.x, 0.f); s.y = fmaxf(s.y, 0.f);
    s.z = fmaxf(s.z, 0.f); s.w = fmaxf(s.w, 0.f);
    float4 wa = reinterpret_cast<const float4*>(W_out)[l];
    float4 wb = reinterpret_cast<const float4*>(W_out + NH)[l];
    float c0 = s.x * wa.x + s.y * wa.y + s.z * wa.z + s.w * wa.w;
    float c1 = s.x * wb.x + s.y * wb.y + s.z * wb.z + s.w * wb.w;

#pragma unroll
    for (int off = 16; off >= 1; off >>= 1) {
        c0 += __shfl_xor(c0, off);
        c1 += __shfl_xor(c1, off);
    }
    if (l == 0) {
        *reinterpret_cast<float2*>(out + (size_t)row * 2) = make_float2(c0, c1);
    }
}

// ---------------------------------------------------------------------------
extern "C" void kernel_launch(void* const* d_in, const int* in_sizes, int n_in,
                              void* d_out, int out_size, void* d_ws, size_t ws_size,
                              hipStream_t stream) {
    const float* u     = (const float*)d_in[0];
    const float* p     = (const float*)d_in[1];
    const float* alpha = (const float*)d_in[2];
    const float* noise = (const float*)d_in[3];
    const float* W_rec = (const float*)d_in[4];
    const float* W_in  = (const float*)d_in[5];
    const float* W_out = (const float*)d_in[6];

    const int B = in_sizes[1] / NH;           // 128
    const int T = in_sizes[0] / (B * NI);     // 3000

    float* out    = (float*)d_out;                    // [B,T,2]
    float* states = out + (size_t)B * T * 2;          // [B,T,128]

    const size_t need = (size_t)B * T * 64 * sizeof(unsigned int);  // 98.3 MB
    if (d_ws != nullptr && ws_size >= need && (B % 32) == 0) {
        unsigned int* dpre = (unsigned int*)d_ws;
        drive_kernel<<<2048, 256, 0, stream>>>(u, p, alpha, noise, W_in,
                                               dpre, B, T);
        dim3 grid(B / 32, NCHB);
        rnn_scan_mfma<<<grid, 64, 0, stream>>>(W_rec, dpre, states, alpha, T);
    } else {
        rnn_scan_fb<<<B, 64, 0, stream>>>(u, p, alpha, noise, W_rec, W_in,
                                          states, T);
    }

    const int rows = B * T;
    out_proj_kernel<<<(rows + 7) / 8, 256, 0, stream>>>(states, W_out, out, rows);
}

// Round 3
// 857.620 us; speedup vs baseline: 1.2057x; 1.1735x over previous
//
#include <hip/hip_runtime.h>
#include <math.h>

#define NH 128          // hidden size
#define NI 6            // input size
#define SIGMA_REC 0.15f
#define WARM 384        // warmup steps (R16/R17: absmax at 384 == f16 floor)
#define NCHB 64         // chunks per batch-group: grid = (B/32) x 64 = 256
                        // blocks (1 wave/CU); path = WARM + 47 = 431 steps.
#define TILE_T 4        // transpose kernel time-tile

typedef __fp16 h2v __attribute__((ext_vector_type(2)));
typedef unsigned int vu4 __attribute__((ext_vector_type(4)));
typedef __fp16 f16x8 __attribute__((ext_vector_type(8)));
typedef float f32x16 __attribute__((ext_vector_type(16)));

__device__ __forceinline__ unsigned int pkh(float a, float b) {
    h2v h = __builtin_amdgcn_cvt_pkrtz(a, b);   // pack 2 f32 -> 2 f16 (RTZ)
    return __builtin_bit_cast(unsigned int, h);
}
#define H2(u) __builtin_bit_cast(h2v, (unsigned int)(u))

struct U6 { float2 a, b, c; };

// fallback-kernel helpers (R12-proven)
#define DOT_OCT(j, xv) \
    c00 = __builtin_amdgcn_fdot2(H2(a##j.x), H2((xv).x), c00, false); \
    c01 = __builtin_amdgcn_fdot2(H2(a##j.y), H2((xv).y), c01, false); \
    c02 = __builtin_amdgcn_fdot2(H2(a##j.z), H2((xv).z), c02, false); \
    c03 = __builtin_amdgcn_fdot2(H2(a##j.w), H2((xv).w), c03, false); \
    c10 = __builtin_amdgcn_fdot2(H2(b##j.x), H2((xv).x), c10, false); \
    c11 = __builtin_amdgcn_fdot2(H2(b##j.y), H2((xv).y), c11, false); \
    c12 = __builtin_amdgcn_fdot2(H2(b##j.z), H2((xv).z), c12, false); \
    c13 = __builtin_amdgcn_fdot2(H2(b##j.w), H2((xv).w), c13, false)

#define LDW(j) vu4 a##j, b##j; { \
    const float4* q0 = reinterpret_cast<const float4*>(wr0 + 8 * (j)); \
    const float4* q1 = reinterpret_cast<const float4*>(wr1 + 8 * (j)); \
    float4 f0 = q0[0], f1 = q0[1], g0 = q1[0], g1 = q1[1]; \
    a##j = (vu4){pkh(f0.x, f0.y), pkh(f0.z, f0.w), pkh(f1.x, f1.y), pkh(f1.z, f1.w)}; \
    b##j = (vu4){pkh(g0.x, g0.y), pkh(g0.z, g0.w), pkh(g1.x, g1.y), pkh(g1.z, g1.w)}; }

#define PIN_AB() \
    asm volatile("" : "+v"(a0), "+v"(a1), "+v"(a2),  "+v"(a3), \
                      "+v"(a4), "+v"(a5), "+v"(a6),  "+v"(a7), \
                      "+v"(a8), "+v"(a9), "+v"(a10), "+v"(a11), \
                      "+v"(a12), "+v"(a13), "+v"(a14), "+v"(a15)); \
    asm volatile("" : "+v"(b0), "+v"(b1), "+v"(b2),  "+v"(b3), \
                      "+v"(b4), "+v"(b5), "+v"(b6),  "+v"(b7), \
                      "+v"(b8), "+v"(b9), "+v"(b10), "+v"(b11), \
                      "+v"(b12), "+v"(b13), "+v"(b14), "+v"(b15))

// ---------------------------------------------------------------------------
// Kernel 0: precompute drive d[b,t,n] = u.W_in + scale*nz + p, packed f16.
// (UNCHANGED — layout dpre[b][t][dword j] = pkh(d(2j), d(2j+1)).)
// ---------------------------------------------------------------------------
__global__ __launch_bounds__(256) void drive_kernel(
    const float* __restrict__ u,      // [B,T,6]
    const float* __restrict__ p,      // [B,128]
    const float* __restrict__ alpha,  // [1]
    const float* __restrict__ noise,  // [B,T,128]
    const float* __restrict__ W_in,   // [128,6]
    unsigned int* __restrict__ dpre,  // [B*T*64]
    int B, int T)
{
    const float av    = alpha[0];
    const float scale = sqrtf(2.0f * av * SIGMA_REC * SIGMA_REC);
    const size_t total = (size_t)B * T * 64;
    for (size_t idx = (size_t)blockIdx.x * 256 + threadIdx.x; idx < total;
         idx += (size_t)gridDim.x * 256) {
        const int    l  = (int)(idx & 63);
        const size_t bt = idx >> 6;
        const int    b  = (int)(bt / (unsigned)T);
        const int    t  = (int)(bt - (size_t)b * T);

        float2 nz = *reinterpret_cast<const float2*>(
            noise + ((size_t)b * T + t) * NH + 2 * l);
        const float2* ur = reinterpret_cast<const float2*>(
            u + ((size_t)b * T + t) * NI);
        float2 ua = ur[0], ub = ur[1], uc = ur[2];
        const float4* wv = reinterpret_cast<const float4*>(W_in + 2 * l * NI);
        float4 w0 = wv[0], w1 = wv[1], w2 = wv[2];   // rows 2l, 2l+1 (12 floats)
        float2 pv = *reinterpret_cast<const float2*>(p + (size_t)b * NH + 2 * l);

        float dx = fmaf(ua.x, w0.x, fmaf(ua.y, w0.y, fmaf(ub.x, w0.z,
                   fmaf(ub.y, w0.w, fmaf(uc.x, w1.x, fmaf(uc.y, w1.y,
                   fmaf(scale, nz.x, pv.x)))))));
        float dy = fmaf(ua.x, w1.z, fmaf(ua.y, w1.w, fmaf(ub.x, w2.x,
                   fmaf(ub.y, w2.y, fmaf(uc.x, w2.z, fmaf(uc.y, w2.w,
                   fmaf(scale, nz.y, pv.y)))))));
        dpre[idx] = pkh(dx, dy);
    }
}

// ---------------------------------------------------------------------------
// R20: transpose dpre -> dpre2, the scan's exact consumption order.
// dpre2 dword addr = ((bg*T + t)*2048) + k*256 + lane*4 + m, holding
// dpre[32bg + (lane&31)][t][j] with j = mt*16 + g*4 + 2*(lane>>5) + r,
// q = mt*4+g = 2k + (m>>1), r = m&1. Scan lane then reads 8 contiguous
// dwordx4 per step (fully coalesced; 128 line-touches/step vs 512).
// LDS-staged so both global sides are coalesced.
// ---------------------------------------------------------------------------
__global__ __launch_bounds__(256) void transpose_d(
    const unsigned int* __restrict__ dpre,   // [B,T,64]
    unsigned int* __restrict__ dpre2,        // [B/32, T, 2048]
    int T)
{
    __shared__ unsigned int lds[256 * 33];   // [(tt*64+j)*33 + col]
    const int tid = threadIdx.x;
    const int t0  = blockIdx.x * TILE_T;
    const int bg  = blockIdx.y;
    const int nt  = min(TILE_T, T - t0);
    if (nt <= 0) return;

    // phase 1: read 32 batches x nt*64 dwords (8 threads per batch row)
    const int bi = tid >> 3;      // batch within group, 0..31
    const int si = tid & 7;
    const unsigned int* src =
        dpre + ((size_t)(bg * 32 + bi) * T + t0) * 64;
#pragma unroll
    for (int c = 0; c < 8; ++c) {
        const int l = 32 * c + 4 * si;           // dword offset in [0,256)
        if (l < nt * 64) {
            uint4 v = *reinterpret_cast<const uint4*>(src + l);
            lds[(l + 0) * 33 + bi] = v.x;
            lds[(l + 1) * 33 + bi] = v.y;
            lds[(l + 2) * 33 + bi] = v.z;
            lds[(l + 3) * 33 + bi] = v.w;
        }
    }
    __syncthreads();

    // phase 2: write coalesced (4 KB contiguous per instruction)
    uint4* out4 = reinterpret_cast<uint4*>(dpre2) + ((size_t)bg * T + t0) * 512;
#pragma unroll
    for (int c = 0; c < 8; ++c) {
        const int idx  = c * 256 + tid;          // uint4 index in [0, nt*512)
        const int tt   = idx >> 9;
        if (tt >= nt) break;
        const int k    = (idx >> 6) & 7;
        const int lane = idx & 63;
        const int hi   = lane >> 5, col = lane & 31;
        unsigned int w[4];
#pragma unroll
        for (int e = 0; e < 4; ++e) {
            const int q  = 2 * k + (e >> 1), r = e & 1;
            const int mt = q >> 2, g = q & 3;
            const int j  = mt * 16 + g * 4 + 2 * hi + r;
            w[e] = lds[(tt * 64 + j) * 33 + col];
        }
        out4[idx] = make_uint4(w[0], w[1], w[2], w[3]);
    }
}

// ---------------------------------------------------------------------------
// R20: MFMA chunked speculative scan, COALESCED d-loads (dpre2 layout),
// depth-2 register double-buffer, halved-shuffle B exchange.
//   A = W tile  : lane holds W[32*mt + (l&31)][16*kk + 8*(l>>5) + 0..7]
//   B = x       : lane holds x[16*kk + 8*(l>>5) + 0..7][b = l&31]
//   C/D         : lane holds (n = 32*mt + 8g + 4hi + 2r1 + delta, b = l&31)
// ---------------------------------------------------------------------------
__global__ __attribute__((amdgpu_flat_work_group_size(64, 64),
                          amdgpu_waves_per_eu(1, 1)))
void rnn_scan_mfma_t(
    const float* __restrict__ W_rec,         // [128,128]
    const unsigned int* __restrict__ dpre2,  // [B/32, T, 2048]
    float* __restrict__ states,              // [B,T,128]
    const float* __restrict__ alpha,         // [1]
    int T)
{
    const int bg    = blockIdx.x;        // batch group (32 rows)
    const int chunk = blockIdx.y;
    const int lane  = threadIdx.x;
    const int col   = lane & 31;         // batch within group
    const int hi    = lane >> 5;
    const int b     = bg * 32 + col;

    const int NS   = T - 1;                     // 2999 steps
    const int S    = (NS + NCHB - 1) / NCHB;    // 47
    const int s0   = chunk * S;
    if (s0 >= NS) return;
    const int e0   = min(NS, s0 + S);
    const int ws   = max(0, s0 - WARM);
    const int NSm1 = NS - 1;

    // ---- W fragments: Wf[mt][kk] covers W[32mt + col][16kk + 8hi .. +7] ----
    f16x8 Wf[4][8];
#pragma unroll
    for (int mt = 0; mt < 4; ++mt) {
        const float* wrow = W_rec + (size_t)(32 * mt + col) * NH + 8 * hi;
#pragma unroll
        for (int kk = 0; kk < 8; ++kk) {
            const float4* q = reinterpret_cast<const float4*>(wrow + 16 * kk);
            float4 f0 = q[0], f1 = q[1];
            vu4 uw = {pkh(f0.x, f0.y), pkh(f0.z, f0.w),
                      pkh(f1.x, f1.y), pkh(f1.z, f1.w)};
            Wf[mt][kk] = __builtin_bit_cast(f16x8, uw);
        }
    }
    // Pin to AGPRs (keeps 128 dwords off the arch-VGPR budget).
    asm volatile("" : "+a"(Wf[0][0]), "+a"(Wf[0][1]), "+a"(Wf[0][2]), "+a"(Wf[0][3]),
                      "+a"(Wf[0][4]), "+a"(Wf[0][5]), "+a"(Wf[0][6]), "+a"(Wf[0][7]),
                      "+a"(Wf[1][0]), "+a"(Wf[1][1]), "+a"(Wf[1][2]), "+a"(Wf[1][3]),
                      "+a"(Wf[1][4]), "+a"(Wf[1][5]), "+a"(Wf[1][6]), "+a"(Wf[1][7]));
    asm volatile("" : "+a"(Wf[2][0]), "+a"(Wf[2][1]), "+a"(Wf[2][2]), "+a"(Wf[2][3]),
                      "+a"(Wf[2][4]), "+a"(Wf[2][5]), "+a"(Wf[2][6]), "+a"(Wf[2][7]),
                      "+a"(Wf[3][0]), "+a"(Wf[3][1]), "+a"(Wf[3][2]), "+a"(Wf[3][3]),
                      "+a"(Wf[3][4]), "+a"(Wf[3][5]), "+a"(Wf[3][6]), "+a"(Wf[3][7]));

    const float av  = alpha[0];
    const float oma = 1.0f - av;
    f32x16 omv, avv, z16;
#pragma unroll
    for (int i = 0; i < 16; ++i) { omv[i] = oma; avv[i] = av; z16[i] = 0.f; }

    // coalesced d base: lane's uint4 stream
    const uint4* d2_b = reinterpret_cast<const uint4*>(dpre2) +
                        (size_t)bg * T * 512 + lane;
    float* st_b = states + (size_t)b * T * NH;

    f32x16 xsv[4];
#pragma unroll
    for (int mt = 0; mt < 4; ++mt) xsv[mt] = z16;
    unsigned Bfd[8][4];
#pragma unroll
    for (int kk = 0; kk < 8; ++kk)
#pragma unroll
        for (int j = 0; j < 4; ++j) Bfd[kk][j] = 0u;

    if (chunk == 0) {   // true t=0 state is zero; store it
        float4 z4 = make_float4(0.f, 0.f, 0.f, 0.f);
#pragma unroll
        for (int mt = 0; mt < 4; ++mt)
#pragma unroll
            for (int g = 0; g < 4; ++g)
                *reinterpret_cast<float4*>(st_b + 32 * mt + 8 * g + 4 * hi) = z4;
    }

    uint4 dA[8], dB[8];
#define LDD2(BUF, tt) { \
    const uint4* rp_ = d2_b + (size_t)(tt) * 512; \
    _Pragma("unroll") \
    for (int k_ = 0; k_ < 8; ++k_) BUF[k_] = rp_[k_ * 64]; }

    LDD2(dA, ws)
    LDD2(dB, min(ws + 1, NSm1))

#define STEPM(tt, BUF) { \
    /* C-init = drive d (f16 -> f32) from uint4 stream; refill BUF for t+2 */ \
    f32x16 C[4]; \
    _Pragma("unroll") \
    for (int k_ = 0; k_ < 8; ++k_) { \
        uint4 V_ = BUF[k_]; \
        const int q0_ = 2 * k_, mt_ = q0_ >> 2, g0_ = q0_ & 3, g1_ = g0_ + 1; \
        h2v a0_ = H2(V_.x), a1_ = H2(V_.y), a2_ = H2(V_.z), a3_ = H2(V_.w); \
        C[mt_][4 * g0_ + 0] = (float)a0_.x; \
        C[mt_][4 * g0_ + 1] = (float)a0_.y; \
        C[mt_][4 * g0_ + 2] = (float)a1_.x; \
        C[mt_][4 * g0_ + 3] = (float)a1_.y; \
        C[mt_][4 * g1_ + 0] = (float)a2_.x; \
        C[mt_][4 * g1_ + 1] = (float)a2_.y; \
        C[mt_][4 * g1_ + 2] = (float)a3_.x; \
        C[mt_][4 * g1_ + 3] = (float)a3_.y; \
    } \
    LDD2(BUF, min((tt) + 2, NSm1)) \
    /* y = W*x + d : 4 independent accumulation chains, kk-major interleave */ \
    _Pragma("unroll") \
    for (int kk_ = 0; kk_ < 8; ++kk_) { \
        vu4 bu_ = {Bfd[kk_][0], Bfd[kk_][1], Bfd[kk_][2], Bfd[kk_][3]}; \
        f16x8 bb_ = __builtin_bit_cast(f16x8, bu_); \
        _Pragma("unroll") \
        for (int mt_ = 0; mt_ < 4; ++mt_) \
            C[mt_] = __builtin_amdgcn_mfma_f32_32x32x16_f16( \
                Wf[mt_][kk_], bb_, C[mt_], 0, 0, 0); \
    } \
    /* blend: x = oma*x + av*relu(y) */ \
    _Pragma("unroll") \
    for (int mt_ = 0; mt_ < 4; ++mt_) { \
        f32x16 r_ = __builtin_elementwise_max(C[mt_], z16); \
        xsv[mt_] = __builtin_elementwise_fma(omv, xsv[mt_], avv * r_); \
    } \
    if ((tt) >= s0) { \
        float* row_ = st_b + (size_t)((tt) + 1) * NH + 4 * hi; \
        _Pragma("unroll") \
        for (int mt_ = 0; mt_ < 4; ++mt_) { \
            _Pragma("unroll") \
            for (int g_ = 0; g_ < 4; ++g_) \
                *reinterpret_cast<float4*>(row_ + 32 * mt_ + 8 * g_) = \
                    make_float4(xsv[mt_][g_ * 4 + 0], \
                                xsv[mt_][g_ * 4 + 1], \
                                xsv[mt_][g_ * 4 + 2], \
                                xsv[mt_][g_ * 4 + 3]); \
        } \
    } \
    /* pack to f16 pairs; single-shuffle cross-half exchange -> B frags.    */ \
    /* lane needs only ONE incoming dword per (q,r): partner's u (hi=0) or  */ \
    /* partner's v (hi=1); send hi?u:v so one shfl serves both directions.  */ \
    unsigned P_[32]; \
    _Pragma("unroll") \
    for (int i_ = 0; i_ < 32; ++i_) \
        P_[i_] = pkh(xsv[i_ >> 3][(2 * i_) & 15], xsv[i_ >> 3][(2 * i_ + 1) & 15]); \
    _Pragma("unroll") \
    for (int mt_ = 0; mt_ < 4; ++mt_) { \
        _Pragma("unroll") \
        for (int gp_ = 0; gp_ < 2; ++gp_) { \
            _Pragma("unroll") \
            for (int r_ = 0; r_ < 2; ++r_) { \
                unsigned u_ = P_[mt_ * 8 + 4 * gp_ + r_]; \
                unsigned v_ = P_[mt_ * 8 + 4 * gp_ + 2 + r_]; \
                unsigned m_ = hi ? u_ : v_; \
                unsigned sm_ = (unsigned)__shfl_xor((int)m_, 32); \
                Bfd[2 * mt_ + gp_][r_]     = hi ? sm_ : u_; \
                Bfd[2 * mt_ + gp_][2 + r_] = hi ? v_  : sm_; \
            } \
        } \
    } }

#pragma unroll 1
    for (int t = ws; t < e0; t += 2) {
        STEPM(t, dA)
        if (t + 1 < e0) { STEPM(t + 1, dB) }
    }
#undef STEPM
#undef LDD2
}

// ---------------------------------------------------------------------------
// R19 scan kept verbatim: mid-size workspace fallback (ws >= 98 MB < 197 MB).
// ---------------------------------------------------------------------------
__global__ __attribute__((amdgpu_flat_work_group_size(64, 64),
                          amdgpu_waves_per_eu(1, 1)))
void rnn_scan_mfma(
    const float* __restrict__ W_rec,        // [128,128]
    const unsigned int* __restrict__ dpre,  // [B*T*64]
    float* __restrict__ states,             // [B,T,128]
    const float* __restrict__ alpha,        // [1]
    int T)
{
    const int bg    = blockIdx.x;
    const int chunk = blockIdx.y;
    const int lane  = threadIdx.x;
    const int col   = lane & 31;
    const int hi    = lane >> 5;
    const int b     = bg * 32 + col;

    const int NS   = T - 1;
    const int S    = (NS + NCHB - 1) / NCHB;
    const int s0   = chunk * S;
    if (s0 >= NS) return;
    const int e0   = min(NS, s0 + S);
    const int ws   = max(0, s0 - WARM);
    const int NSm1 = NS - 1;

    f16x8 Wf[4][8];
#pragma unroll
    for (int mt = 0; mt < 4; ++mt) {
        const float* wrow = W_rec + (size_t)(32 * mt + col) * NH + 8 * hi;
#pragma unroll
        for (int kk = 0; kk < 8; ++kk) {
            const float4* q = reinterpret_cast<const float4*>(wrow + 16 * kk);
            float4 f0 = q[0], f1 = q[1];
            vu4 uw = {pkh(f0.x, f0.y), pkh(f0.z, f0.w),
                      pkh(f1.x, f1.y), pkh(f1.z, f1.w)};
            Wf[mt][kk] = __builtin_bit_cast(f16x8, uw);
        }
    }
    asm volatile("" : "+a"(Wf[0][0]), "+a"(Wf[0][1]), "+a"(Wf[0][2]), "+a"(Wf[0][3]),
                      "+a"(Wf[0][4]), "+a"(Wf[0][5]), "+a"(Wf[0][6]), "+a"(Wf[0][7]),
                      "+a"(Wf[1][0]), "+a"(Wf[1][1]), "+a"(Wf[1][2]), "+a"(Wf[1][3]),
                      "+a"(Wf[1][4]), "+a"(Wf[1][5]), "+a"(Wf[1][6]), "+a"(Wf[1][7]));
    asm volatile("" : "+a"(Wf[2][0]), "+a"(Wf[2][1]), "+a"(Wf[2][2]), "+a"(Wf[2][3]),
                      "+a"(Wf[2][4]), "+a"(Wf[2][5]), "+a"(Wf[2][6]), "+a"(Wf[2][7]),
                      "+a"(Wf[3][0]), "+a"(Wf[3][1]), "+a"(Wf[3][2]), "+a"(Wf[3][3]),
                      "+a"(Wf[3][4]), "+a"(Wf[3][5]), "+a"(Wf[3][6]), "+a"(Wf[3][7]));

    const float av  = alpha[0];
    const float oma = 1.0f - av;
    f32x16 omv, avv, z16;
#pragma unroll
    for (int i = 0; i < 16; ++i) { omv[i] = oma; avv[i] = av; z16[i] = 0.f; }

    const unsigned int* dp_b = dpre + (size_t)b * T * 64;
    float* st_b = states + (size_t)b * T * NH;

    f32x16 xsv[4];
#pragma unroll
    for (int mt = 0; mt < 4; ++mt) xsv[mt] = z16;
    unsigned Bfd[8][4];
#pragma unroll
    for (int kk = 0; kk < 8; ++kk)
#pragma unroll
        for (int j = 0; j < 4; ++j) Bfd[kk][j] = 0u;

    if (chunk == 0) {
        float4 z4 = make_float4(0.f, 0.f, 0.f, 0.f);
#pragma unroll
        for (int mt = 0; mt < 4; ++mt)
#pragma unroll
            for (int g = 0; g < 4; ++g)
                *reinterpret_cast<float4*>(st_b + 32 * mt + 8 * g + 4 * hi) = z4;
    }

    uint2 dA[16];
#define LDDM(BUF, tt) { \
    const unsigned int* rp_ = dp_b + (size_t)(tt) * 64 + 2 * hi; \
    _Pragma("unroll") \
    for (int mt_ = 0; mt_ < 4; ++mt_) { \
        _Pragma("unroll") \
        for (int g_ = 0; g_ < 4; ++g_) \
            BUF[mt_ * 4 + g_] = \
                *reinterpret_cast<const uint2*>(rp_ + mt_ * 16 + g_ * 4); \
    } }

    LDDM(dA, ws)

#define STEPM(tt) { \
    f32x16 C[4]; \
    _Pragma("unroll") \
    for (int mt_ = 0; mt_ < 4; ++mt_) { \
        _Pragma("unroll") \
        for (int g_ = 0; g_ < 4; ++g_) { \
            uint2 dw_ = dA[mt_ * 4 + g_]; \
            h2v dl_ = H2(dw_.x), dh_ = H2(dw_.y); \
            C[mt_][4 * g_ + 0] = (float)dl_.x; \
            C[mt_][4 * g_ + 1] = (float)dl_.y; \
            C[mt_][4 * g_ + 2] = (float)dh_.x; \
            C[mt_][4 * g_ + 3] = (float)dh_.y; \
        } \
    } \
    LDDM(dA, min((tt) + 1, NSm1)) \
    _Pragma("unroll") \
    for (int kk_ = 0; kk_ < 8; ++kk_) { \
        vu4 bu_ = {Bfd[kk_][0], Bfd[kk_][1], Bfd[kk_][2], Bfd[kk_][3]}; \
        f16x8 bb_ = __builtin_bit_cast(f16x8, bu_); \
        _Pragma("unroll") \
        for (int mt_ = 0; mt_ < 4; ++mt_) \
            C[mt_] = __builtin_amdgcn_mfma_f32_32x32x16_f16( \
                Wf[mt_][kk_], bb_, C[mt_], 0, 0, 0); \
    } \
    _Pragma("unroll") \
    for (int mt_ = 0; mt_ < 4; ++mt_) { \
        f32x16 r_ = __builtin_elementwise_max(C[mt_], z16); \
        xsv[mt_] = __builtin_elementwise_fma(omv, xsv[mt_], avv * r_); \
    } \
    if ((tt) >= s0) { \
        float* row_ = st_b + (size_t)((tt) + 1) * NH + 4 * hi; \
        _Pragma("unroll") \
        for (int mt_ = 0; mt_ < 4; ++mt_) { \
            _Pragma("unroll") \
            for (int g_ = 0; g_ < 4; ++g_) \
                *reinterpret_cast<float4*>(row_ + 32 * mt_ + 8 * g_) = \
                    make_float4(xsv[mt_][g_ * 4 + 0], \
                                xsv[mt_][g_ * 4 + 1], \
                                xsv[mt_][g_ * 4 + 2], \
                                xsv[mt_][g_ * 4 + 3]); \
        } \
    } \
    unsigned P_[32]; \
    _Pragma("unroll") \
    for (int i_ = 0; i_ < 32; ++i_) \
        P_[i_] = pkh(xsv[i_ >> 3][(2 * i_) & 15], xsv[i_ >> 3][(2 * i_ + 1) & 15]); \
    _Pragma("unroll") \
    for (int mt_ = 0; mt_ < 4; ++mt_) { \
        _Pragma("unroll") \
        for (int gp_ = 0; gp_ < 2; ++gp_) { \
            _Pragma("unroll") \
            for (int r_ = 0; r_ < 2; ++r_) { \
                unsigned u_ = P_[mt_ * 8 + 4 * gp_ + r_]; \
                unsigned v_ = P_[mt_ * 8 + 4 * gp_ + 2 + r_]; \
                unsigned m_ = hi ? u_ : v_; \
                unsigned sm_ = (unsigned)__shfl_xor((int)m_, 32); \
                Bfd[2 * mt_ + gp_][r_]     = hi ? sm_ : u_; \
                Bfd[2 * mt_ + gp_][2 + r_] = hi ? v_  : sm_; \
            } \
        } \
    } }

#pragma unroll 1
    for (int t = ws; t < e0; ++t) {
        STEPM(t)
    }
#undef STEPM
#undef LDDM
}

// ---------------------------------------------------------------------------
// Fallback scan (R12 verbatim, exact, non-chunked): if ws_size too small.
// ---------------------------------------------------------------------------
__global__ __attribute__((amdgpu_flat_work_group_size(64, 64),
                          amdgpu_waves_per_eu(1, 1)))
void rnn_scan_fb(
    const float* __restrict__ u, const float* __restrict__ p,
    const float* __restrict__ alpha, const float* __restrict__ noise,
    const float* __restrict__ W_rec, const float* __restrict__ W_in,
    float* __restrict__ states, int T)
{
    const int b    = blockIdx.x;
    const int lane = threadIdx.x;
    const int n0   = lane * 2;

    __shared__ unsigned int xsh[64];

    const float* wr0 = W_rec + (size_t)n0 * NH;
    const float* wr1 = wr0 + NH;
    LDW(0)  LDW(1)  LDW(2)  LDW(3)  LDW(4)  LDW(5)  LDW(6)  LDW(7)
    LDW(8)  LDW(9)  LDW(10) LDW(11) LDW(12) LDW(13) LDW(14) LDW(15)
    PIN_AB();

    const float wiA0 = W_in[n0 * NI + 0], wiA1 = W_in[n0 * NI + 1];
    const float wiA2 = W_in[n0 * NI + 2], wiA3 = W_in[n0 * NI + 3];
    const float wiA4 = W_in[n0 * NI + 4], wiA5 = W_in[n0 * NI + 5];
    const float wiB0 = W_in[(n0 + 1) * NI + 0], wiB1 = W_in[(n0 + 1) * NI + 1];
    const float wiB2 = W_in[(n0 + 1) * NI + 2], wiB3 = W_in[(n0 + 1) * NI + 3];
    const float wiB4 = W_in[(n0 + 1) * NI + 4], wiB5 = W_in[(n0 + 1) * NI + 5];

    const float2 pn   = *reinterpret_cast<const float2*>(p + (size_t)b * NH + n0);
    const float av    = alpha[0];
    const float oma   = 1.0f - av;
    const float scale = sqrtf(2.0f * av * SIGMA_REC * SIGMA_REC);

    const float* noise_b = noise + (size_t)b * T * NH + n0;
    unsigned int zv;
    asm volatile("v_mov_b32 %0, 0" : "=v"(zv));
    const float* u_b = u + (size_t)b * T * NI + zv;
    float* st_ptr = states + (size_t)b * T * NH + n0 + NH;

    xsh[lane] = 0u;
    *reinterpret_cast<float2*>(states + (size_t)b * T * NH + n0) = make_float2(0.f, 0.f);
    float xo0 = 0.0f, xo1 = 0.0f;

    auto LDnz = [&](int t) {
        return *reinterpret_cast<const float2*>(noise_b + (size_t)t * NH);
    };
    auto loadU = [&](int t) {
        const float2* up = reinterpret_cast<const float2*>(u_b + (size_t)t * NI);
        U6 r; r.a = up[0]; r.b = up[1]; r.c = up[2]; return r;
    };
    auto mkd = [&](float2 nz, const U6& uu) {
        float dx = fmaf(uu.a.x, wiA0, fmaf(uu.a.y, wiA1, fmaf(uu.b.x, wiA2,
                   fmaf(uu.b.y, wiA3, fmaf(uu.c.x, wiA4, fmaf(uu.c.y, wiA5,
                   fmaf(scale, nz.x, pn.x)))))));
        float dy = fmaf(uu.a.x, wiB0, fmaf(uu.a.y, wiB1, fmaf(uu.b.x, wiB2,
                   fmaf(uu.b.y, wiB3, fmaf(uu.c.x, wiB4, fmaf(uu.c.y, wiB5,
                   fmaf(scale, nz.y, pn.y)))))));
        return make_float2(dx, dy);
    };
    auto step = [&](float2 d) {
        const vu4* xr = reinterpret_cast<const vu4*>(xsh);
        float c00 = 0.f, c01 = 0.f, c02 = 0.f, c03 = 0.f;
        float c10 = 0.f, c11 = 0.f, c12 = 0.f, c13 = 0.f;
        vu4 xv0 = xr[0], xv1 = xr[1], xv2 = xr[2], xv3 = xr[3];
        vu4 xv4 = xr[4], xv5 = xr[5], xv6 = xr[6], xv7 = xr[7];
        DOT_OCT(0, xv0);  DOT_OCT(1, xv1);  DOT_OCT(2, xv2);  DOT_OCT(3, xv3);
        vu4 xv8 = xr[8], xv9 = xr[9], xv10 = xr[10], xv11 = xr[11];
        DOT_OCT(4, xv4);  DOT_OCT(5, xv5);  DOT_OCT(6, xv6);  DOT_OCT(7, xv7);
        vu4 xv12 = xr[12], xv13 = xr[13], xv14 = xr[14], xv15 = xr[15];
        DOT_OCT(8, xv8);  DOT_OCT(9, xv9);  DOT_OCT(10, xv10); DOT_OCT(11, xv11);
        DOT_OCT(12, xv12); DOT_OCT(13, xv13); DOT_OCT(14, xv14); DOT_OCT(15, xv15);
        float pre0 = ((c00 + c01) + (c02 + c03)) + d.x;
        float pre1 = ((c10 + c11) + (c12 + c13)) + d.y;
        float xn0 = fmaf(oma, xo0, av * fmaxf(pre0, 0.f));
        float xn1 = fmaf(oma, xo1, av * fmaxf(pre1, 0.f));
        xo0 = xn0; xo1 = xn1;
        *reinterpret_cast<float2*>(st_ptr) = make_float2(xn0, xn1);
        st_ptr += NH;
        xsh[lane] = pkh(xn0, xn1);
    };

    float2 nz0 = LDnz(0), nz1 = LDnz(1), nz2 = LDnz(2), nz3 = LDnz(3);
    U6 u0 = loadU(0), u1 = loadU(1), u2 = loadU(2), u3 = loadU(3);
    float2 nzA0 = LDnz(4), nzA1 = LDnz(5);   U6 uA0 = loadU(4), uA1 = loadU(5);
    float2 nzB0 = LDnz(6), nzB1 = LDnz(7);   U6 uB0 = loadU(6), uB1 = loadU(7);
    float2 d0 = mkd(nz0, u0), d1 = mkd(nz1, u1);
    float2 d2 = mkd(nz2, u2), d3 = mkd(nz3, u3);

    int t = 0;
    for (; t + 1 < T - 1; t += 2) {
        const int t8 = min(t + 8, T - 1), t9 = min(t + 9, T - 1);
        float2 nzC0 = LDnz(t8), nzC1 = LDnz(t9);
        U6 uC0 = loadU(t8), uC1 = loadU(t9);
        float2 dE = mkd(nzA0, uA0), dF = mkd(nzA1, uA1);
        step(d0);
        step(d1);
        d0 = d2; d1 = d3; d2 = dE; d3 = dF;
        nzA0 = nzB0; nzA1 = nzB1; uA0 = uB0; uA1 = uB1;
        nzB0 = nzC0; nzB1 = nzC1; uB0 = uC0; uB1 = uC1;
    }
    if (t < T - 1) step(d0);
}

// ---------------------------------------------------------------------------
// Projection: out[r,o] = sum_n relu(states[r,n]) * W_out[o,n]
// ---------------------------------------------------------------------------
__global__ __launch_bounds__(256) void out_proj_kernel(
    const float* __restrict__ states,  // [rows,128]
    const float* __restrict__ W_out,   // [2,128]
    float* __restrict__ out,           // [rows,2]
    int rows)
{
    const int wave = threadIdx.x >> 6;
    const int lane = threadIdx.x & 63;
    const int l    = lane & 31;
    const int row  = blockIdx.x * 8 + wave * 2 + (lane >> 5);
    if (row >= rows) return;

    float4 s = *reinterpret_cast<const float4*>(states + (size_t)row * NH + l * 4);
    s.x = fmaxf(s.x, 0.f); s.y = fmaxf(s.y, 0.f);
    s.z = fmaxf(s.z, 0.f); s.w = fmaxf(s.w, 0.f);
    float4 wa = reinterpret_cast<const float4*>(W_out)[l];
    float4 wb = reinterpret_cast<const float4*>(W_out + NH)[l];
    float c0 = s.x * wa.x + s.y * wa.y + s.z * wa.z + s.w * wa.w;
    float c1 = s.x * wb.x + s.y * wb.y + s.z * wb.z + s.w * wb.w;

#pragma unroll
    for (int off = 16; off >= 1; off >>= 1) {
        c0 += __shfl_xor(c0, off);
        c1 += __shfl_xor(c1, off);
    }
    if (l == 0) {
        *reinterpret_cast<float2*>(out + (size_t)row * 2) = make_float2(c0, c1);
    }
}

// ---------------------------------------------------------------------------
extern "C" void kernel_launch(void* const* d_in, const int* in_sizes, int n_in,
                              void* d_out, int out_size, void* d_ws, size_t ws_size,
                              hipStream_t stream) {
    const float* u     = (const float*)d_in[0];
    const float* p     = (const float*)d_in[1];
    const float* alpha = (const float*)d_in[2];
    const float* noise = (const float*)d_in[3];
    const float* W_rec = (const float*)d_in[4];
    const float* W_in  = (const float*)d_in[5];
    const float* W_out = (const float*)d_in[6];

    const int B = in_sizes[1] / NH;           // 128
    const int T = in_sizes[0] / (B * NI);     // 3000

    float* out    = (float*)d_out;                    // [B,T,2]
    float* states = out + (size_t)B * T * 2;          // [B,T,128]

    const size_t need1 = (size_t)B * T * 64 * sizeof(unsigned int);  // 98.3 MB
    if (d_ws != nullptr && ws_size >= 2 * need1 && (B % 32) == 0) {
        // full path: drive -> transpose -> coalesced MFMA scan
        unsigned int* dpre  = (unsigned int*)d_ws;
        unsigned int* dpre2 = (unsigned int*)((char*)d_ws + need1);
        drive_kernel<<<2048, 256, 0, stream>>>(u, p, alpha, noise, W_in,
                                               dpre, B, T);
        dim3 tgrid((T + TILE_T - 1) / TILE_T, B / 32);
        transpose_d<<<tgrid, 256, 0, stream>>>(dpre, dpre2, T);
        dim3 grid(B / 32, NCHB);
        rnn_scan_mfma_t<<<grid, 64, 0, stream>>>(W_rec, dpre2, states, alpha, T);
    } else if (d_ws != nullptr && ws_size >= need1 && (B % 32) == 0) {
        unsigned int* dpre = (unsigned int*)d_ws;
        drive_kernel<<<2048, 256, 0, stream>>>(u, p, alpha, noise, W_in,
                                               dpre, B, T);
        dim3 grid(B / 32, NCHB);
        rnn_scan_mfma<<<grid, 64, 0, stream>>>(W_rec, dpre, states, alpha, T);
    } else {
        rnn_scan_fb<<<B, 64, 0, stream>>>(u, p, alpha, noise, W_rec, W_in,
                                          states, T);
    }

    const int rows = B * T;
    out_proj_kernel<<<(rows + 7) / 8, 256, 0, stream>>>(states, W_out, out, rows);
}